// Round 1
// baseline (2058.069 us; speedup 1.0000x reference)
//
#include <hip/hip_runtime.h>
#include <hip/hip_bf16.h>

// GIN 3-layer + mean-pool + MLP head for MI355X.
// Stage plan (all on `stream`, graph-capture safe):
//   per layer l: memset(agg); scatter_add(h_l, src, dst -> agg); gemm_elu(h_l, agg -> h_{l+1})
//   pool (sorted-batch segmented sum, few atomics); head MLP (512 blocks).
//
// ws layout: agg (N*64 f32) | hA (N*64 f32) | hB (N*64 f32) | sums (G*64) | cnts (G)

__device__ __forceinline__ float elu_f(float x) {
  return x > 0.0f ? x : expm1f(x);
}

// agg[dst[e]][f] += h[src[e]][f]; one thread per (edge, feature).
template <int LOGF>
__global__ void scatter_add_kernel(const float* __restrict__ h,
                                   const int* __restrict__ src,
                                   const int* __restrict__ dst,
                                   float* __restrict__ agg,
                                   int E) {
  const int F = 1 << LOGF;
  const long long total = (long long)E << LOGF;
  const long long stride = (long long)gridDim.x * blockDim.x;
  for (long long i = (long long)blockIdx.x * blockDim.x + threadIdx.x; i < total;
       i += stride) {
    const int e = (int)(i >> LOGF);
    const int f = (int)(i & (F - 1));
    const int s = src[e];
    const int d = dst[e];
    const float v = h[((long long)s << LOGF) + f];
    atomicAdd(&agg[((long long)d << LOGF) + f], v);
  }
}

// out[n][f] = elu( b[f] + sum_k (h[n][k] + agg[n][k]) * W[k][f] )
template <int FI, int FO>
__global__ void gin_mlp_kernel(const float* __restrict__ h,
                               const float* __restrict__ agg,
                               const float* __restrict__ W,
                               const float* __restrict__ b,
                               float* __restrict__ out,
                               int N) {
  __shared__ float sW[FI * FO];
  for (int i = threadIdx.x; i < FI * FO; i += blockDim.x) sW[i] = W[i];
  __syncthreads();
  const int npb = 256 / FO;  // nodes per block per iteration
  const int f = threadIdx.x % FO;
  const int nl = threadIdx.x / FO;
  const float bias = b[f];
  for (int n0 = blockIdx.x * npb; n0 < N; n0 += gridDim.x * npb) {
    const int n = n0 + nl;
    if (n < N) {
      const float* hr = h + (long long)n * FI;
      const float* ar = agg + (long long)n * FI;
      float acc = bias;
#pragma unroll
      for (int k = 0; k < FI; ++k) {
        acc += (hr[k] + ar[k]) * sW[k * FO + f];
      }
      out[(long long)n * FO + f] = elu_f(acc);
    }
  }
}

// Sorted-batch segmented mean-pool (sums + counts). 64 lanes = 1 feature row.
// Each lane-group walks a contiguous node chunk, flushing atomics only when
// the graph id changes (batch is sorted -> ~2 flushes per group).
__global__ void pool_kernel(const float* __restrict__ h,
                            const int* __restrict__ batch,
                            float* __restrict__ sums,
                            float* __restrict__ cnts,
                            int N) {
  const int groupsPerBlock = blockDim.x >> 6;
  const int grp = blockIdx.x * groupsPerBlock + (threadIdx.x >> 6);
  const int ngrp = gridDim.x * groupsPerBlock;
  const int f = threadIdx.x & 63;
  const int chunk = (N + ngrp - 1) / ngrp;
  const int n0 = grp * chunk;
  const int n1 = min(N, n0 + chunk);
  if (n0 >= n1) return;
  int g = batch[n0];
  float acc = 0.0f;
  float cnt = 0.0f;
  for (int n = n0; n < n1; ++n) {
    const int bg = batch[n];
    if (bg != g) {
      atomicAdd(&sums[(long long)g * 64 + f], acc);
      if (f == 0) atomicAdd(&cnts[g], cnt);
      acc = 0.0f;
      cnt = 0.0f;
      g = bg;
    }
    acc += h[(long long)n * 64 + f];
    cnt += 1.0f;
  }
  atomicAdd(&sums[(long long)g * 64 + f], acc);
  if (f == 0) atomicAdd(&cnts[g], cnt);
}

// Per-graph head MLP: mean -> 64x64 elu -> 64x32 elu -> 32x1.
__global__ void head_kernel(const float* __restrict__ sums,
                            const float* __restrict__ cnts,
                            const float* __restrict__ Wf1, const float* __restrict__ bf1,
                            const float* __restrict__ Wf2, const float* __restrict__ bf2,
                            const float* __restrict__ Wf3, const float* __restrict__ bf3,
                            float* __restrict__ out, int G) {
  __shared__ float s0[64];
  __shared__ float s1[64];
  __shared__ float s2[32];
  const int g = blockIdx.x;
  const int t = threadIdx.x;
  const float c = fmaxf(cnts[g], 1.0f);
  s0[t] = sums[(long long)g * 64 + t] / c;
  __syncthreads();
  float acc = bf1[t];
#pragma unroll
  for (int k = 0; k < 64; ++k) acc += s0[k] * Wf1[k * 64 + t];
  s1[t] = elu_f(acc);
  __syncthreads();
  if (t < 32) {
    float a2 = bf2[t];
#pragma unroll
    for (int k = 0; k < 64; ++k) a2 += s1[k] * Wf2[k * 32 + t];
    s2[t] = elu_f(a2) * Wf3[t];
  }
  __syncthreads();
  if (t == 0) {
    float r = bf3[0];
#pragma unroll
    for (int k = 0; k < 32; ++k) r += s2[k];
    out[g] = r;
  }
}

extern "C" void kernel_launch(void* const* d_in, const int* in_sizes, int n_in,
                              void* d_out, int out_size, void* d_ws, size_t ws_size,
                              hipStream_t stream) {
  const float* x   = (const float*)d_in[0];
  const int* ei    = (const int*)d_in[1];
  const int* batch = (const int*)d_in[2];
  // d_in[3] = num_graphs scalar (G == out_size)
  const float* W1  = (const float*)d_in[4];
  const float* b1  = (const float*)d_in[5];
  const float* W2  = (const float*)d_in[6];
  const float* b2  = (const float*)d_in[7];
  const float* W3  = (const float*)d_in[8];
  const float* b3  = (const float*)d_in[9];
  const float* Wf1 = (const float*)d_in[10];
  const float* bf1 = (const float*)d_in[11];
  const float* Wf2 = (const float*)d_in[12];
  const float* bf2 = (const float*)d_in[13];
  const float* Wf3 = (const float*)d_in[14];
  const float* bf3 = (const float*)d_in[15];

  const int N = in_sizes[0] / 64;
  const int E = in_sizes[1] / 2;
  const int G = out_size;
  const int* src = ei;
  const int* dst = ei + E;

  char* ws = (char*)d_ws;
  size_t off = 0;
  auto alloc = [&](size_t bytes) -> void* {
    void* p = ws + off;
    off = (off + bytes + 255) & ~(size_t)255;
    return p;
  };
  float* agg  = (float*)alloc((size_t)N * 64 * 4);
  float* hA   = (float*)alloc((size_t)N * 64 * 4);
  float* hB   = (float*)alloc((size_t)N * 64 * 4);
  float* sums = (float*)alloc((size_t)G * 64 * 4);
  float* cnts = (float*)alloc((size_t)G * 4);
  float* out  = (float*)d_out;

  // Layer 1: x (64) -> hA (32)
  hipMemsetAsync(agg, 0, (size_t)N * 64 * 4, stream);
  scatter_add_kernel<6><<<2048, 256, 0, stream>>>(x, src, dst, agg, E);
  gin_mlp_kernel<64, 32><<<2048, 256, 0, stream>>>(x, agg, W1, b1, hA, N);

  // Layer 2: hA (32) -> hB (64)
  hipMemsetAsync(agg, 0, (size_t)N * 32 * 4, stream);
  scatter_add_kernel<5><<<2048, 256, 0, stream>>>(hA, src, dst, agg, E);
  gin_mlp_kernel<32, 64><<<2048, 256, 0, stream>>>(hA, agg, W2, b2, hB, N);

  // Layer 3: hB (64) -> hA (64)
  hipMemsetAsync(agg, 0, (size_t)N * 64 * 4, stream);
  scatter_add_kernel<6><<<2048, 256, 0, stream>>>(hB, src, dst, agg, E);
  gin_mlp_kernel<64, 64><<<2048, 256, 0, stream>>>(hB, agg, W3, b3, hA, N);

  // Mean pool (sorted batch) + head MLP
  hipMemsetAsync(sums, 0, (size_t)G * 64 * 4, stream);
  hipMemsetAsync(cnts, 0, (size_t)G * 4, stream);
  pool_kernel<<<128, 256, 0, stream>>>(hA, batch, sums, cnts, N);
  head_kernel<<<G, 64, 0, stream>>>(sums, cnts, Wf1, bf1, Wf2, bf2, Wf3, bf3, out, G);
}

// Round 2
// 1116.975 us; speedup vs baseline: 1.8425x; 1.8425x over previous
//
#include <hip/hip_runtime.h>
#include <hip/hip_bf16.h>

// GIN 3-layer + mean-pool + MLP head for MI355X (gfx950).
//
// Round-2 plan: replace f32-atomic scatter (device-scope atomics write through
// the XCD-coherence point at ~1.9 TB/s = the round-1 bottleneck) with a
// pull-mode CSR gather:
//   once:  hist(dst) -> deg; scan(deg) -> rowptr; fill -> eidx  (int atomics only)
//   per layer: fused gather+MLP, one wave per node, lane = feature,
//              W column in VGPRs, readlane-broadcast dot products.
//
// ws layout: deg/cursor | rowptr | blksum | eidx | hA | hB | sums | cnts

__device__ __forceinline__ float elu_f(float x) {
  return x > 0.0f ? x : expm1f(x);
}

// ---------------- CSR build ----------------

__global__ void hist_kernel(const int* __restrict__ dst, int* __restrict__ deg, int E) {
  const int stride = gridDim.x * blockDim.x;
  for (int e = blockIdx.x * blockDim.x + threadIdx.x; e < E; e += stride)
    atomicAdd(&deg[dst[e]], 1);
}

#define SCAN_BLOCK 256
// inclusive scan of deg chunks -> rowptr[i+1]; chunk totals -> blksum
__global__ void scan1_kernel(const int* __restrict__ deg, int* __restrict__ rowptr,
                             int* __restrict__ blksum, int N) {
  __shared__ int s[SCAN_BLOCK];
  const int i = blockIdx.x * SCAN_BLOCK + threadIdx.x;
  s[threadIdx.x] = (i < N) ? deg[i] : 0;
  __syncthreads();
#pragma unroll
  for (int off = 1; off < SCAN_BLOCK; off <<= 1) {
    int t = (threadIdx.x >= off) ? s[threadIdx.x - off] : 0;
    __syncthreads();
    s[threadIdx.x] += t;
    __syncthreads();
  }
  if (i < N) rowptr[i + 1] = s[threadIdx.x];
  if (threadIdx.x == SCAN_BLOCK - 1) blksum[blockIdx.x] = s[threadIdx.x];
  if (blockIdx.x == 0 && threadIdx.x == 0) rowptr[0] = 0;
}

// single-block inclusive scan of blksum (nblk <= 1024)
__global__ void scan2_kernel(int* __restrict__ blksum, int nblk) {
  __shared__ int s[1024];
  const int t = threadIdx.x;
  s[t] = (t < nblk) ? blksum[t] : 0;
  __syncthreads();
#pragma unroll
  for (int off = 1; off < 1024; off <<= 1) {
    int v = (t >= off) ? s[t - off] : 0;
    __syncthreads();
    s[t] += v;
    __syncthreads();
  }
  if (t < nblk) blksum[t] = s[t];
}

__global__ void scan3_kernel(int* __restrict__ rowptr, const int* __restrict__ blksum, int N) {
  if (blockIdx.x == 0) return;
  const int i = blockIdx.x * SCAN_BLOCK + threadIdx.x;
  if (i < N) rowptr[i + 1] += blksum[blockIdx.x - 1];
}

__global__ void fill_kernel(const int* __restrict__ src, const int* __restrict__ dst,
                            int* __restrict__ cursor, int* __restrict__ eidx, int E) {
  const int stride = gridDim.x * blockDim.x;
  for (int e = blockIdx.x * blockDim.x + threadIdx.x; e < E; e += stride) {
    const int p = atomicAdd(&cursor[dst[e]], 1);
    eidx[p] = src[e];
  }
}

// ---------------- fused gather + MLP layer ----------------
// One wave per node. lane carries feature k for the gather; W column for
// output fo=lane%FO lives in VGPRs; dot product via readlane broadcast.
template <int FI, int FO>
__global__ __launch_bounds__(256) void gin_layer_kernel(
    const float* __restrict__ h, const int* __restrict__ rowptr,
    const int* __restrict__ eidx, const float* __restrict__ W,
    const float* __restrict__ b, float* __restrict__ out, int N) {
  const int lane = threadIdx.x & 63;
  const int wid = blockIdx.x * (blockDim.x >> 6) + (threadIdx.x >> 6);
  const int nw = gridDim.x * (blockDim.x >> 6);
  const int fo = lane & (FO - 1);
  float wcol[FI];
#pragma unroll
  for (int k = 0; k < FI; ++k) wcol[k] = W[k * FO + fo];
  const float bias = b[fo];
  const bool flane = (lane < FI);

  for (int n = wid; n < N; n += nw) {
    const int r0 = rowptr[n];
    const int r1 = rowptr[n + 1];
    float a0 = 0.0f, a1 = 0.0f, a2 = 0.0f, a3 = 0.0f;
    if (flane) a0 = h[(long long)n * FI + lane];
    int j = r0;
    for (; j + 4 <= r1; j += 4) {
      const int s0 = eidx[j];
      const int s1 = eidx[j + 1];
      const int s2 = eidx[j + 2];
      const int s3 = eidx[j + 3];
      float v0 = 0.0f, v1 = 0.0f, v2 = 0.0f, v3 = 0.0f;
      if (flane) {
        v0 = h[(long long)s0 * FI + lane];
        v1 = h[(long long)s1 * FI + lane];
        v2 = h[(long long)s2 * FI + lane];
        v3 = h[(long long)s3 * FI + lane];
      }
      a0 += v0; a1 += v1; a2 += v2; a3 += v3;
    }
    for (; j < r1; ++j) {
      const int s = eidx[j];
      if (flane) a0 += h[(long long)s * FI + lane];
    }
    const float acc = (a0 + a1) + (a2 + a3);
    // MLP: o = bias + sum_k acc_k * W[k][fo], readlane broadcast of acc_k
    float o0 = bias, o1 = 0.0f;
#pragma unroll
    for (int k = 0; k < FI; k += 2) {
      const float ak0 = __int_as_float(__builtin_amdgcn_readlane(__float_as_int(acc), k));
      const float ak1 = __int_as_float(__builtin_amdgcn_readlane(__float_as_int(acc), k + 1));
      o0 = fmaf(ak0, wcol[k], o0);
      o1 = fmaf(ak1, wcol[k + 1], o1);
    }
    if (lane < FO) out[(long long)n * FO + lane] = elu_f(o0 + o1);
  }
}

// ---------------- pooling + head (unchanged from round 1) ----------------

__global__ void pool_kernel(const float* __restrict__ h,
                            const int* __restrict__ batch,
                            float* __restrict__ sums,
                            float* __restrict__ cnts,
                            int N) {
  const int groupsPerBlock = blockDim.x >> 6;
  const int grp = blockIdx.x * groupsPerBlock + (threadIdx.x >> 6);
  const int ngrp = gridDim.x * groupsPerBlock;
  const int f = threadIdx.x & 63;
  const int chunk = (N + ngrp - 1) / ngrp;
  const int n0 = grp * chunk;
  const int n1 = min(N, n0 + chunk);
  if (n0 >= n1) return;
  int g = batch[n0];
  float acc = 0.0f;
  float cnt = 0.0f;
  for (int n = n0; n < n1; ++n) {
    const int bg = batch[n];
    if (bg != g) {
      atomicAdd(&sums[(long long)g * 64 + f], acc);
      if (f == 0) atomicAdd(&cnts[g], cnt);
      acc = 0.0f;
      cnt = 0.0f;
      g = bg;
    }
    acc += h[(long long)n * 64 + f];
    cnt += 1.0f;
  }
  atomicAdd(&sums[(long long)g * 64 + f], acc);
  if (f == 0) atomicAdd(&cnts[g], cnt);
}

__global__ void head_kernel(const float* __restrict__ sums,
                            const float* __restrict__ cnts,
                            const float* __restrict__ Wf1, const float* __restrict__ bf1,
                            const float* __restrict__ Wf2, const float* __restrict__ bf2,
                            const float* __restrict__ Wf3, const float* __restrict__ bf3,
                            float* __restrict__ out, int G) {
  __shared__ float s0[64];
  __shared__ float s1[64];
  __shared__ float s2[32];
  const int g = blockIdx.x;
  const int t = threadIdx.x;
  const float c = fmaxf(cnts[g], 1.0f);
  s0[t] = sums[(long long)g * 64 + t] / c;
  __syncthreads();
  float acc = bf1[t];
#pragma unroll
  for (int k = 0; k < 64; ++k) acc += s0[k] * Wf1[k * 64 + t];
  s1[t] = elu_f(acc);
  __syncthreads();
  if (t < 32) {
    float a2 = bf2[t];
#pragma unroll
    for (int k = 0; k < 64; ++k) a2 += s1[k] * Wf2[k * 32 + t];
    s2[t] = elu_f(a2) * Wf3[t];
  }
  __syncthreads();
  if (t == 0) {
    float r = bf3[0];
#pragma unroll
    for (int k = 0; k < 32; ++k) r += s2[k];
    out[g] = r;
  }
}

extern "C" void kernel_launch(void* const* d_in, const int* in_sizes, int n_in,
                              void* d_out, int out_size, void* d_ws, size_t ws_size,
                              hipStream_t stream) {
  const float* x   = (const float*)d_in[0];
  const int* ei    = (const int*)d_in[1];
  const int* batch = (const int*)d_in[2];
  const float* W1  = (const float*)d_in[4];
  const float* b1  = (const float*)d_in[5];
  const float* W2  = (const float*)d_in[6];
  const float* b2  = (const float*)d_in[7];
  const float* W3  = (const float*)d_in[8];
  const float* b3  = (const float*)d_in[9];
  const float* Wf1 = (const float*)d_in[10];
  const float* bf1 = (const float*)d_in[11];
  const float* Wf2 = (const float*)d_in[12];
  const float* bf2 = (const float*)d_in[13];
  const float* Wf3 = (const float*)d_in[14];
  const float* bf3 = (const float*)d_in[15];

  const int N = in_sizes[0] / 64;
  const int E = in_sizes[1] / 2;
  const int G = out_size;
  const int* src = ei;
  const int* dst = ei + E;
  const int nblk_scan = (N + SCAN_BLOCK - 1) / SCAN_BLOCK;

  char* ws = (char*)d_ws;
  size_t off = 0;
  auto alloc = [&](size_t bytes) -> void* {
    void* p = ws + off;
    off = (off + bytes + 255) & ~(size_t)255;
    return p;
  };
  int* deg     = (int*)alloc((size_t)N * 4);          // also reused as cursor
  int* rowptr  = (int*)alloc((size_t)(N + 1) * 4);
  int* cursor  = (int*)alloc((size_t)N * 4);
  int* blksum  = (int*)alloc((size_t)nblk_scan * 4);
  int* eidx    = (int*)alloc((size_t)E * 4);
  float* hA    = (float*)alloc((size_t)N * 64 * 4);
  float* hB    = (float*)alloc((size_t)N * 64 * 4);
  float* sums  = (float*)alloc((size_t)G * 64 * 4);
  float* cnts  = (float*)alloc((size_t)G * 4);
  float* out   = (float*)d_out;

  // ---- CSR build (by dst) ----
  hipMemsetAsync(deg, 0, (size_t)N * 4, stream);
  hist_kernel<<<2048, 256, 0, stream>>>(dst, deg, E);
  scan1_kernel<<<nblk_scan, SCAN_BLOCK, 0, stream>>>(deg, rowptr, blksum, N);
  scan2_kernel<<<1, 1024, 0, stream>>>(blksum, nblk_scan);
  scan3_kernel<<<nblk_scan, SCAN_BLOCK, 0, stream>>>(rowptr, blksum, N);
  hipMemcpyAsync(cursor, rowptr, (size_t)N * 4, hipMemcpyDeviceToDevice, stream);
  fill_kernel<<<2048, 256, 0, stream>>>(src, dst, cursor, eidx, E);

  // ---- layers ----
  gin_layer_kernel<64, 32><<<1024, 256, 0, stream>>>(x,  rowptr, eidx, W1, b1, hA, N);
  gin_layer_kernel<32, 64><<<1024, 256, 0, stream>>>(hA, rowptr, eidx, W2, b2, hB, N);
  gin_layer_kernel<64, 64><<<1024, 256, 0, stream>>>(hB, rowptr, eidx, W3, b3, hA, N);

  // ---- mean pool + head ----
  hipMemsetAsync(sums, 0, (size_t)G * 64 * 4, stream);
  hipMemsetAsync(cnts, 0, (size_t)G * 4, stream);
  pool_kernel<<<128, 256, 0, stream>>>(hA, batch, sums, cnts, N);
  head_kernel<<<G, 64, 0, stream>>>(sums, cnts, Wf1, bf1, Wf2, bf2, Wf3, bf3, out, G);
}

// Round 3
// 875.821 us; speedup vs baseline: 2.3499x; 1.2753x over previous
//
#include <hip/hip_runtime.h>
#include <hip/hip_bf16.h>

// GIN 3-layer + mean-pool + MLP head for MI355X (gfx950).
//
// Round-3: fill_kernel had 16x write amplification (196MB WRITE_SIZE for a
// 12.8MB eidx array) -- random 4B scatters across 8 incoherent XCD L2s.
// Fix: XCD-range partitioning (bid%8 -> dst node range), so each XCD's eidx
// writes land in a private 1.6MB region that fits its L2 and lines fill up
// before writeback. Also: FI=32 layer now uses full 64-lane waves (2 edges
// per iteration, half-wave each, shfl_xor(32) combine).

__device__ __forceinline__ float elu_f(float x) {
  return x > 0.0f ? x : expm1f(x);
}

// ---------------- CSR build ----------------

__global__ void hist_kernel(const int* __restrict__ dst, int* __restrict__ deg, int E) {
  const int stride = gridDim.x * blockDim.x;
  for (int e = blockIdx.x * blockDim.x + threadIdx.x; e < E; e += stride)
    atomicAdd(&deg[dst[e]], 1);
}

#define SCAN_BLOCK 256
__global__ void scan1_kernel(const int* __restrict__ deg, int* __restrict__ rowptr,
                             int* __restrict__ blksum, int N) {
  __shared__ int s[SCAN_BLOCK];
  const int i = blockIdx.x * SCAN_BLOCK + threadIdx.x;
  s[threadIdx.x] = (i < N) ? deg[i] : 0;
  __syncthreads();
#pragma unroll
  for (int off = 1; off < SCAN_BLOCK; off <<= 1) {
    int t = (threadIdx.x >= off) ? s[threadIdx.x - off] : 0;
    __syncthreads();
    s[threadIdx.x] += t;
    __syncthreads();
  }
  if (i < N) rowptr[i + 1] = s[threadIdx.x];
  if (threadIdx.x == SCAN_BLOCK - 1) blksum[blockIdx.x] = s[threadIdx.x];
  if (blockIdx.x == 0 && threadIdx.x == 0) rowptr[0] = 0;
}

__global__ void scan2_kernel(int* __restrict__ blksum, int nblk) {
  __shared__ int s[1024];
  const int t = threadIdx.x;
  s[t] = (t < nblk) ? blksum[t] : 0;
  __syncthreads();
#pragma unroll
  for (int off = 1; off < 1024; off <<= 1) {
    int v = (t >= off) ? s[t - off] : 0;
    __syncthreads();
    s[t] += v;
    __syncthreads();
  }
  if (t < nblk) blksum[t] = s[t];
}

__global__ void scan3_kernel(int* __restrict__ rowptr, const int* __restrict__ blksum, int N) {
  if (blockIdx.x == 0) return;
  const int i = blockIdx.x * SCAN_BLOCK + threadIdx.x;
  if (i < N) rowptr[i + 1] += blksum[blockIdx.x - 1];
}

// XCD-range partitioned fill: blocks with bid%8==k only handle dst in node
// range k -> each XCD's eidx/cursor writes stay in a ~1.6MB L2-resident
// region (write amplification ~1x). Mapping is a perf heuristic only.
__global__ void fill_kernel(const int* __restrict__ src, const int* __restrict__ dst,
                            int* __restrict__ cursor, int* __restrict__ eidx,
                            int E, int N) {
  const int xcd = blockIdx.x & 7;
  const int lo = (int)((long long)xcd * N >> 3);
  const int hi = (int)((long long)(xcd + 1) * N >> 3);
  const int gblk = blockIdx.x >> 3;
  const int nblk = gridDim.x >> 3;
  const int stride = nblk * blockDim.x;
  for (int e = gblk * blockDim.x + threadIdx.x; e < E; e += stride) {
    const int d = dst[e];
    if (d >= lo && d < hi) {
      const int p = atomicAdd(&cursor[d], 1);
      eidx[p] = src[e];
    }
  }
}

// ---------------- fused gather + MLP layers ----------------

// FI=64 variant (FO = 32 or 64): one wave per node, lane = feature.
template <int FO>
__global__ __launch_bounds__(256) void gin_layer64_kernel(
    const float* __restrict__ h, const int* __restrict__ rowptr,
    const int* __restrict__ eidx, const float* __restrict__ W,
    const float* __restrict__ b, float* __restrict__ out, int N) {
  const int lane = threadIdx.x & 63;
  const int wid = blockIdx.x * (blockDim.x >> 6) + (threadIdx.x >> 6);
  const int nw = gridDim.x * (blockDim.x >> 6);
  const int fo = lane & (FO - 1);
  float wcol[64];
#pragma unroll
  for (int k = 0; k < 64; ++k) wcol[k] = W[k * FO + fo];
  const float bias = b[fo];

  for (int n = wid; n < N; n += nw) {
    const int r0 = rowptr[n];
    const int r1 = rowptr[n + 1];
    float a0 = h[(long long)n * 64 + lane];
    float a1 = 0.0f, a2 = 0.0f, a3 = 0.0f;
    int j = r0;
    for (; j + 4 <= r1; j += 4) {
      const int s0 = eidx[j];
      const int s1 = eidx[j + 1];
      const int s2 = eidx[j + 2];
      const int s3 = eidx[j + 3];
      a0 += h[(long long)s0 * 64 + lane];
      a1 += h[(long long)s1 * 64 + lane];
      a2 += h[(long long)s2 * 64 + lane];
      a3 += h[(long long)s3 * 64 + lane];
    }
    for (; j < r1; ++j) a0 += h[(long long)eidx[j] * 64 + lane];
    const float acc = (a0 + a1) + (a2 + a3);
    float o0 = bias, o1 = 0.0f;
#pragma unroll
    for (int k = 0; k < 64; k += 2) {
      const float ak0 = __int_as_float(__builtin_amdgcn_readlane(__float_as_int(acc), k));
      const float ak1 = __int_as_float(__builtin_amdgcn_readlane(__float_as_int(acc), k + 1));
      o0 = fmaf(ak0, wcol[k], o0);
      o1 = fmaf(ak1, wcol[k + 1], o1);
    }
    if (lane < FO) out[(long long)n * FO + lane] = elu_f(o0 + o1);
  }
}

// FI=32, FO=64: one wave per node, 2 edges per iteration (half-wave each),
// full 64-lane gather utilization; halves combined with shfl_xor(32).
__global__ __launch_bounds__(256) void gin_layer32_kernel(
    const float* __restrict__ h, const int* __restrict__ rowptr,
    const int* __restrict__ eidx, const float* __restrict__ W,
    const float* __restrict__ b, float* __restrict__ out, int N) {
  const int lane = threadIdx.x & 63;
  const int sub = lane >> 5;      // which edge of the pair
  const int fi = lane & 31;       // input feature
  const int wid = blockIdx.x * (blockDim.x >> 6) + (threadIdx.x >> 6);
  const int nw = gridDim.x * (blockDim.x >> 6);
  float wcol[32];
#pragma unroll
  for (int k = 0; k < 32; ++k) wcol[k] = W[k * 64 + lane];
  const float bias = b[lane];

  for (int n = wid; n < N; n += nw) {
    const int r0 = rowptr[n];
    const int r1 = rowptr[n + 1];
    float a0 = 0.0f, a1 = 0.0f, a2 = 0.0f, a3 = 0.0f;
    int j = r0;
    for (; j + 8 <= r1; j += 8) {
      const int s0 = eidx[j + 0 + sub];
      const int s1 = eidx[j + 2 + sub];
      const int s2 = eidx[j + 4 + sub];
      const int s3 = eidx[j + 6 + sub];
      a0 += h[(long long)s0 * 32 + fi];
      a1 += h[(long long)s1 * 32 + fi];
      a2 += h[(long long)s2 * 32 + fi];
      a3 += h[(long long)s3 * 32 + fi];
    }
    for (; j < r1; j += 2) {
      const int idx = j + sub;
      if (idx < r1) a0 += h[(long long)eidx[idx] * 32 + fi];
    }
    float acc = (a0 + a1) + (a2 + a3);
    acc += __shfl_xor(acc, 32, 64);                    // combine edge halves
    acc += h[(long long)n * 32 + fi];                  // self term
    // lanes 0..31 hold features 0..31 (lanes 32..63 duplicate them)
    float o0 = bias, o1 = 0.0f;
#pragma unroll
    for (int k = 0; k < 32; k += 2) {
      const float ak0 = __int_as_float(__builtin_amdgcn_readlane(__float_as_int(acc), k));
      const float ak1 = __int_as_float(__builtin_amdgcn_readlane(__float_as_int(acc), k + 1));
      o0 = fmaf(ak0, wcol[k], o0);
      o1 = fmaf(ak1, wcol[k + 1], o1);
    }
    out[(long long)n * 64 + lane] = elu_f(o0 + o1);
  }
}

// ---------------- pooling + head ----------------

__global__ void pool_kernel(const float* __restrict__ h,
                            const int* __restrict__ batch,
                            float* __restrict__ sums,
                            float* __restrict__ cnts,
                            int N) {
  const int groupsPerBlock = blockDim.x >> 6;
  const int grp = blockIdx.x * groupsPerBlock + (threadIdx.x >> 6);
  const int ngrp = gridDim.x * groupsPerBlock;
  const int f = threadIdx.x & 63;
  const int chunk = (N + ngrp - 1) / ngrp;
  const int n0 = grp * chunk;
  const int n1 = min(N, n0 + chunk);
  if (n0 >= n1) return;
  int g = batch[n0];
  float acc = 0.0f;
  float cnt = 0.0f;
  for (int n = n0; n < n1; ++n) {
    const int bg = batch[n];
    if (bg != g) {
      atomicAdd(&sums[(long long)g * 64 + f], acc);
      if (f == 0) atomicAdd(&cnts[g], cnt);
      acc = 0.0f;
      cnt = 0.0f;
      g = bg;
    }
    acc += h[(long long)n * 64 + f];
    cnt += 1.0f;
  }
  atomicAdd(&sums[(long long)g * 64 + f], acc);
  if (f == 0) atomicAdd(&cnts[g], cnt);
}

__global__ void head_kernel(const float* __restrict__ sums,
                            const float* __restrict__ cnts,
                            const float* __restrict__ Wf1, const float* __restrict__ bf1,
                            const float* __restrict__ Wf2, const float* __restrict__ bf2,
                            const float* __restrict__ Wf3, const float* __restrict__ bf3,
                            float* __restrict__ out, int G) {
  __shared__ float s0[64];
  __shared__ float s1[64];
  __shared__ float s2[32];
  const int g = blockIdx.x;
  const int t = threadIdx.x;
  const float c = fmaxf(cnts[g], 1.0f);
  s0[t] = sums[(long long)g * 64 + t] / c;
  __syncthreads();
  float acc = bf1[t];
#pragma unroll
  for (int k = 0; k < 64; ++k) acc += s0[k] * Wf1[k * 64 + t];
  s1[t] = elu_f(acc);
  __syncthreads();
  if (t < 32) {
    float a2 = bf2[t];
#pragma unroll
    for (int k = 0; k < 64; ++k) a2 += s1[k] * Wf2[k * 32 + t];
    s2[t] = elu_f(a2) * Wf3[t];
  }
  __syncthreads();
  if (t == 0) {
    float r = bf3[0];
#pragma unroll
    for (int k = 0; k < 32; ++k) r += s2[k];
    out[g] = r;
  }
}

extern "C" void kernel_launch(void* const* d_in, const int* in_sizes, int n_in,
                              void* d_out, int out_size, void* d_ws, size_t ws_size,
                              hipStream_t stream) {
  const float* x   = (const float*)d_in[0];
  const int* ei    = (const int*)d_in[1];
  const int* batch = (const int*)d_in[2];
  const float* W1  = (const float*)d_in[4];
  const float* b1  = (const float*)d_in[5];
  const float* W2  = (const float*)d_in[6];
  const float* b2  = (const float*)d_in[7];
  const float* W3  = (const float*)d_in[8];
  const float* b3  = (const float*)d_in[9];
  const float* Wf1 = (const float*)d_in[10];
  const float* bf1 = (const float*)d_in[11];
  const float* Wf2 = (const float*)d_in[12];
  const float* bf2 = (const float*)d_in[13];
  const float* Wf3 = (const float*)d_in[14];
  const float* bf3 = (const float*)d_in[15];

  const int N = in_sizes[0] / 64;
  const int E = in_sizes[1] / 2;
  const int G = out_size;
  const int* src = ei;
  const int* dst = ei + E;
  const int nblk_scan = (N + SCAN_BLOCK - 1) / SCAN_BLOCK;

  char* ws = (char*)d_ws;
  size_t off = 0;
  auto alloc = [&](size_t bytes) -> void* {
    void* p = ws + off;
    off = (off + bytes + 255) & ~(size_t)255;
    return p;
  };
  int* deg     = (int*)alloc((size_t)N * 4);
  int* rowptr  = (int*)alloc((size_t)(N + 1) * 4);
  int* cursor  = (int*)alloc((size_t)N * 4);
  int* blksum  = (int*)alloc((size_t)nblk_scan * 4);
  int* eidx    = (int*)alloc((size_t)E * 4);
  float* hA    = (float*)alloc((size_t)N * 64 * 4);
  float* hB    = (float*)alloc((size_t)N * 64 * 4);
  float* sums  = (float*)alloc((size_t)G * 64 * 4);
  float* cnts  = (float*)alloc((size_t)G * 4);
  float* out   = (float*)d_out;

  // ---- CSR build (by dst) ----
  hipMemsetAsync(deg, 0, (size_t)N * 4, stream);
  hist_kernel<<<2048, 256, 0, stream>>>(dst, deg, E);
  scan1_kernel<<<nblk_scan, SCAN_BLOCK, 0, stream>>>(deg, rowptr, blksum, N);
  scan2_kernel<<<1, 1024, 0, stream>>>(blksum, nblk_scan);
  scan3_kernel<<<nblk_scan, SCAN_BLOCK, 0, stream>>>(rowptr, blksum, N);
  hipMemcpyAsync(cursor, rowptr, (size_t)N * 4, hipMemcpyDeviceToDevice, stream);
  fill_kernel<<<2048, 256, 0, stream>>>(src, dst, cursor, eidx, E, N);

  // ---- layers ----
  gin_layer64_kernel<32><<<2048, 256, 0, stream>>>(x,  rowptr, eidx, W1, b1, hA, N);
  gin_layer32_kernel<<<2048, 256, 0, stream>>>(hA, rowptr, eidx, W2, b2, hB, N);
  gin_layer64_kernel<64><<<2048, 256, 0, stream>>>(hB, rowptr, eidx, W3, b3, hA, N);

  // ---- mean pool + head ----
  hipMemsetAsync(sums, 0, (size_t)G * 64 * 4, stream);
  hipMemsetAsync(cnts, 0, (size_t)G * 4, stream);
  pool_kernel<<<512, 256, 0, stream>>>(hA, batch, sums, cnts, N);
  head_kernel<<<G, 64, 0, stream>>>(sums, cnts, Wf1, bf1, Wf2, bf2, Wf3, bf3, out, G);
}

// Round 4
// 727.342 us; speedup vs baseline: 2.8296x; 1.2041x over previous
//
#include <hip/hip_runtime.h>
#include <hip/hip_bf16.h>

// GIN 3-layer + mean-pool + MLP head for MI355X (gfx950).
//
// Round-4: gather layers were latency-bound (1KB/wave in flight). Rework
// gather to dwordx4: 16 lanes x 16B = one 256B row -> 4 edges per vmem
// instruction, 2-deep unroll = 2KB/wave in flight. Cross-group reduce via
// shfl_xor(16,32); readlane MLP on float4 accumulators. FI=32 layer uses
// 8 lanes/row -> 8 edges per instruction.

typedef float f4 __attribute__((ext_vector_type(4)));

__device__ __forceinline__ float elu_f(float x) {
  return x > 0.0f ? x : expm1f(x);
}

__device__ __forceinline__ float rl(float v, int q) {
  return __int_as_float(__builtin_amdgcn_readlane(__float_as_int(v), q));
}

// ---------------- CSR build ----------------

__global__ void hist_kernel(const int* __restrict__ dst, int* __restrict__ deg, int E) {
  const int stride = gridDim.x * blockDim.x;
  for (int e = blockIdx.x * blockDim.x + threadIdx.x; e < E; e += stride)
    atomicAdd(&deg[dst[e]], 1);
}

#define SCAN_BLOCK 256
__global__ void scan1_kernel(const int* __restrict__ deg, int* __restrict__ rowptr,
                             int* __restrict__ blksum, int N) {
  __shared__ int s[SCAN_BLOCK];
  const int i = blockIdx.x * SCAN_BLOCK + threadIdx.x;
  s[threadIdx.x] = (i < N) ? deg[i] : 0;
  __syncthreads();
#pragma unroll
  for (int off = 1; off < SCAN_BLOCK; off <<= 1) {
    int t = (threadIdx.x >= off) ? s[threadIdx.x - off] : 0;
    __syncthreads();
    s[threadIdx.x] += t;
    __syncthreads();
  }
  if (i < N) rowptr[i + 1] = s[threadIdx.x];
  if (threadIdx.x == SCAN_BLOCK - 1) blksum[blockIdx.x] = s[threadIdx.x];
  if (blockIdx.x == 0 && threadIdx.x == 0) rowptr[0] = 0;
}

__global__ void scan2_kernel(int* __restrict__ blksum, int nblk) {
  __shared__ int s[1024];
  const int t = threadIdx.x;
  s[t] = (t < nblk) ? blksum[t] : 0;
  __syncthreads();
#pragma unroll
  for (int off = 1; off < 1024; off <<= 1) {
    int v = (t >= off) ? s[t - off] : 0;
    __syncthreads();
    s[t] += v;
    __syncthreads();
  }
  if (t < nblk) blksum[t] = s[t];
}

__global__ void scan3_kernel(int* __restrict__ rowptr, const int* __restrict__ blksum, int N) {
  if (blockIdx.x == 0) return;
  const int i = blockIdx.x * SCAN_BLOCK + threadIdx.x;
  if (i < N) rowptr[i + 1] += blksum[blockIdx.x - 1];
}

// XCD-range partitioned fill (round-3 win: write amplification ~1x).
__global__ void fill_kernel(const int* __restrict__ src, const int* __restrict__ dst,
                            int* __restrict__ cursor, int* __restrict__ eidx,
                            int E, int N) {
  const int xcd = blockIdx.x & 7;
  const int lo = (int)((long long)xcd * N >> 3);
  const int hi = (int)((long long)(xcd + 1) * N >> 3);
  const int gblk = blockIdx.x >> 3;
  const int nblk = gridDim.x >> 3;
  const int stride = nblk * blockDim.x;
  for (int e = gblk * blockDim.x + threadIdx.x; e < E; e += stride) {
    const int d = dst[e];
    if (d >= lo && d < hi) {
      const int p = atomicAdd(&cursor[d], 1);
      eidx[p] = src[e];
    }
  }
}

// ---------------- fused gather + MLP layers ----------------

// FI=64: 4 groups of 16 lanes; each group loads a full 256B row as dwordx4.
// 4 edges per vmem instruction, 2-deep unroll (8 edges/iter).
template <int FO>
__global__ __launch_bounds__(256) void gin_layer64_kernel(
    const float* __restrict__ h, const int* __restrict__ rowptr,
    const int* __restrict__ eidx, const float* __restrict__ W,
    const float* __restrict__ b, float* __restrict__ out, int N) {
  const int lane = threadIdx.x & 63;
  const int grp = lane >> 4;       // 0..3 : which edge of the quad
  const int li = lane & 15;        // 16B chunk within row (features li*4..li*4+3)
  const int wid = blockIdx.x * (blockDim.x >> 6) + (threadIdx.x >> 6);
  const int nw = gridDim.x * (blockDim.x >> 6);
  const int fo = lane & (FO - 1);
  float wcol[64];
#pragma unroll
  for (int k = 0; k < 64; ++k) wcol[k] = W[k * FO + fo];
  const float bias = b[fo];

  for (int n = wid; n < N; n += nw) {
    const int r0 = rowptr[n];
    const int cnt = rowptr[n + 1] - r0;
    const f4 self = *reinterpret_cast<const f4*>(h + (long long)n * 64 + li * 4);
    f4 a0 = {0.f, 0.f, 0.f, 0.f}, a1 = {0.f, 0.f, 0.f, 0.f};
    int i = grp;
    for (; i + 4 < cnt; i += 8) {
      const int s0 = eidx[r0 + i];
      const int s1 = eidx[r0 + i + 4];
      const f4 v0 = *reinterpret_cast<const f4*>(h + (long long)s0 * 64 + li * 4);
      const f4 v1 = *reinterpret_cast<const f4*>(h + (long long)s1 * 64 + li * 4);
      a0 += v0;
      a1 += v1;
    }
    if (i < cnt) {
      const int s = eidx[r0 + i];
      a0 += *reinterpret_cast<const f4*>(h + (long long)s * 64 + li * 4);
    }
    f4 a = a0 + a1;
    // combine the 4 edge-groups (lanes differing in bits 4,5)
    a.x += __shfl_xor(a.x, 16, 64); a.y += __shfl_xor(a.y, 16, 64);
    a.z += __shfl_xor(a.z, 16, 64); a.w += __shfl_xor(a.w, 16, 64);
    a.x += __shfl_xor(a.x, 32, 64); a.y += __shfl_xor(a.y, 32, 64);
    a.z += __shfl_xor(a.z, 32, 64); a.w += __shfl_xor(a.w, 32, 64);
    a += self;
    // MLP: o[fo] = bias + sum_k a_k * W[k][fo]; a_k lives in lane k/4, comp k%4
    float o0 = bias, o1 = 0.0f;
#pragma unroll
    for (int q = 0; q < 16; ++q) {
      o0 = fmaf(rl(a.x, q), wcol[4 * q + 0], o0);
      o1 = fmaf(rl(a.y, q), wcol[4 * q + 1], o1);
      o0 = fmaf(rl(a.z, q), wcol[4 * q + 2], o0);
      o1 = fmaf(rl(a.w, q), wcol[4 * q + 3], o1);
    }
    if (lane < FO) out[(long long)n * FO + lane] = elu_f(o0 + o1);
  }
}

// FI=32, FO=64: 8 groups of 8 lanes; 128B row as dwordx4 -> 8 edges per
// vmem instruction, 2-deep unroll (16 edges/iter).
__global__ __launch_bounds__(256) void gin_layer32_kernel(
    const float* __restrict__ h, const int* __restrict__ rowptr,
    const int* __restrict__ eidx, const float* __restrict__ W,
    const float* __restrict__ b, float* __restrict__ out, int N) {
  const int lane = threadIdx.x & 63;
  const int grp = lane >> 3;       // 0..7
  const int li = lane & 7;         // features li*4..li*4+3
  const int wid = blockIdx.x * (blockDim.x >> 6) + (threadIdx.x >> 6);
  const int nw = gridDim.x * (blockDim.x >> 6);
  float wcol[32];
#pragma unroll
  for (int k = 0; k < 32; ++k) wcol[k] = W[k * 64 + lane];
  const float bias = b[lane];

  for (int n = wid; n < N; n += nw) {
    const int r0 = rowptr[n];
    const int cnt = rowptr[n + 1] - r0;
    const f4 self = *reinterpret_cast<const f4*>(h + (long long)n * 32 + li * 4);
    f4 a0 = {0.f, 0.f, 0.f, 0.f}, a1 = {0.f, 0.f, 0.f, 0.f};
    int i = grp;
    for (; i + 8 < cnt; i += 16) {
      const int s0 = eidx[r0 + i];
      const int s1 = eidx[r0 + i + 8];
      const f4 v0 = *reinterpret_cast<const f4*>(h + (long long)s0 * 32 + li * 4);
      const f4 v1 = *reinterpret_cast<const f4*>(h + (long long)s1 * 32 + li * 4);
      a0 += v0;
      a1 += v1;
    }
    if (i < cnt) {
      const int s = eidx[r0 + i];
      a0 += *reinterpret_cast<const f4*>(h + (long long)s * 32 + li * 4);
    }
    f4 a = a0 + a1;
    a.x += __shfl_xor(a.x, 8, 64);  a.y += __shfl_xor(a.y, 8, 64);
    a.z += __shfl_xor(a.z, 8, 64);  a.w += __shfl_xor(a.w, 8, 64);
    a.x += __shfl_xor(a.x, 16, 64); a.y += __shfl_xor(a.y, 16, 64);
    a.z += __shfl_xor(a.z, 16, 64); a.w += __shfl_xor(a.w, 16, 64);
    a.x += __shfl_xor(a.x, 32, 64); a.y += __shfl_xor(a.y, 32, 64);
    a.z += __shfl_xor(a.z, 32, 64); a.w += __shfl_xor(a.w, 32, 64);
    a += self;
    float o0 = bias, o1 = 0.0f;
#pragma unroll
    for (int q = 0; q < 8; ++q) {
      o0 = fmaf(rl(a.x, q), wcol[4 * q + 0], o0);
      o1 = fmaf(rl(a.y, q), wcol[4 * q + 1], o1);
      o0 = fmaf(rl(a.z, q), wcol[4 * q + 2], o0);
      o1 = fmaf(rl(a.w, q), wcol[4 * q + 3], o1);
    }
    out[(long long)n * 64 + lane] = elu_f(o0 + o1);
  }
}

// ---------------- pooling + head ----------------

__global__ void pool_kernel(const float* __restrict__ h,
                            const int* __restrict__ batch,
                            float* __restrict__ sums,
                            float* __restrict__ cnts,
                            int N) {
  const int groupsPerBlock = blockDim.x >> 6;
  const int grp = blockIdx.x * groupsPerBlock + (threadIdx.x >> 6);
  const int ngrp = gridDim.x * groupsPerBlock;
  const int f = threadIdx.x & 63;
  const int chunk = (N + ngrp - 1) / ngrp;
  const int n0 = grp * chunk;
  const int n1 = min(N, n0 + chunk);
  if (n0 >= n1) return;
  int g = batch[n0];
  float acc = 0.0f;
  float cnt = 0.0f;
  for (int n = n0; n < n1; ++n) {
    const int bg = batch[n];
    if (bg != g) {
      atomicAdd(&sums[(long long)g * 64 + f], acc);
      if (f == 0) atomicAdd(&cnts[g], cnt);
      acc = 0.0f;
      cnt = 0.0f;
      g = bg;
    }
    acc += h[(long long)n * 64 + f];
    cnt += 1.0f;
  }
  atomicAdd(&sums[(long long)g * 64 + f], acc);
  if (f == 0) atomicAdd(&cnts[g], cnt);
}

__global__ void head_kernel(const float* __restrict__ sums,
                            const float* __restrict__ cnts,
                            const float* __restrict__ Wf1, const float* __restrict__ bf1,
                            const float* __restrict__ Wf2, const float* __restrict__ bf2,
                            const float* __restrict__ Wf3, const float* __restrict__ bf3,
                            float* __restrict__ out, int G) {
  __shared__ float s0[64];
  __shared__ float s1[64];
  __shared__ float s2[32];
  const int g = blockIdx.x;
  const int t = threadIdx.x;
  const float c = fmaxf(cnts[g], 1.0f);
  s0[t] = sums[(long long)g * 64 + t] / c;
  __syncthreads();
  float acc = bf1[t];
#pragma unroll
  for (int k = 0; k < 64; ++k) acc += s0[k] * Wf1[k * 64 + t];
  s1[t] = elu_f(acc);
  __syncthreads();
  if (t < 32) {
    float a2 = bf2[t];
#pragma unroll
    for (int k = 0; k < 64; ++k) a2 += s1[k] * Wf2[k * 32 + t];
    s2[t] = elu_f(a2) * Wf3[t];
  }
  __syncthreads();
  if (t == 0) {
    float r = bf3[0];
#pragma unroll
    for (int k = 0; k < 32; ++k) r += s2[k];
    out[g] = r;
  }
}

extern "C" void kernel_launch(void* const* d_in, const int* in_sizes, int n_in,
                              void* d_out, int out_size, void* d_ws, size_t ws_size,
                              hipStream_t stream) {
  const float* x   = (const float*)d_in[0];
  const int* ei    = (const int*)d_in[1];
  const int* batch = (const int*)d_in[2];
  const float* W1  = (const float*)d_in[4];
  const float* b1  = (const float*)d_in[5];
  const float* W2  = (const float*)d_in[6];
  const float* b2  = (const float*)d_in[7];
  const float* W3  = (const float*)d_in[8];
  const float* b3  = (const float*)d_in[9];
  const float* Wf1 = (const float*)d_in[10];
  const float* bf1 = (const float*)d_in[11];
  const float* Wf2 = (const float*)d_in[12];
  const float* bf2 = (const float*)d_in[13];
  const float* Wf3 = (const float*)d_in[14];
  const float* bf3 = (const float*)d_in[15];

  const int N = in_sizes[0] / 64;
  const int E = in_sizes[1] / 2;
  const int G = out_size;
  const int* src = ei;
  const int* dst = ei + E;
  const int nblk_scan = (N + SCAN_BLOCK - 1) / SCAN_BLOCK;

  char* ws = (char*)d_ws;
  size_t off = 0;
  auto alloc = [&](size_t bytes) -> void* {
    void* p = ws + off;
    off = (off + bytes + 255) & ~(size_t)255;
    return p;
  };
  int* deg     = (int*)alloc((size_t)N * 4);
  int* rowptr  = (int*)alloc((size_t)(N + 1) * 4);
  int* cursor  = (int*)alloc((size_t)N * 4);
  int* blksum  = (int*)alloc((size_t)nblk_scan * 4);
  int* eidx    = (int*)alloc((size_t)E * 4);
  float* hA    = (float*)alloc((size_t)N * 64 * 4);
  float* hB    = (float*)alloc((size_t)N * 64 * 4);
  float* sums  = (float*)alloc((size_t)G * 64 * 4);
  float* cnts  = (float*)alloc((size_t)G * 4);
  float* out   = (float*)d_out;

  // ---- CSR build (by dst) ----
  hipMemsetAsync(deg, 0, (size_t)N * 4, stream);
  hist_kernel<<<2048, 256, 0, stream>>>(dst, deg, E);
  scan1_kernel<<<nblk_scan, SCAN_BLOCK, 0, stream>>>(deg, rowptr, blksum, N);
  scan2_kernel<<<1, 1024, 0, stream>>>(blksum, nblk_scan);
  scan3_kernel<<<nblk_scan, SCAN_BLOCK, 0, stream>>>(rowptr, blksum, N);
  hipMemcpyAsync(cursor, rowptr, (size_t)N * 4, hipMemcpyDeviceToDevice, stream);
  fill_kernel<<<2048, 256, 0, stream>>>(src, dst, cursor, eidx, E, N);

  // ---- layers ----
  gin_layer64_kernel<32><<<2048, 256, 0, stream>>>(x,  rowptr, eidx, W1, b1, hA, N);
  gin_layer32_kernel<<<2048, 256, 0, stream>>>(hA, rowptr, eidx, W2, b2, hB, N);
  gin_layer64_kernel<64><<<2048, 256, 0, stream>>>(hB, rowptr, eidx, W3, b3, hA, N);

  // ---- mean pool + head ----
  hipMemsetAsync(sums, 0, (size_t)G * 64 * 4, stream);
  hipMemsetAsync(cnts, 0, (size_t)G * 4, stream);
  pool_kernel<<<512, 256, 0, stream>>>(hA, batch, sums, cnts, N);
  head_kernel<<<G, 64, 0, stream>>>(sums, cnts, Wf1, bf1, Wf2, bf2, Wf3, bf3, out, G);
}

// Round 6
// 519.545 us; speedup vs baseline: 3.9613x; 1.4000x over previous
//
#include <hip/hip_runtime.h>
#include <hip/hip_bf16.h>

// GIN 3-layer + mean-pool + MLP head for MI355X (gfx950).
//
// Round-5 (resubmit; previous attempt hit GPUAcquisitionTimeout, never ran):
// device-scope atomics write through to HBM (~31B/atomic measured: hist 100MB
// WRITE for 3.2M atomics). Replace atomic hist+fill CSR build with an
// atomic-free two-level counting sort:
//   A : per-chunk LDS bucket histograms (bucket=128 nodes) -> bhist[C][K]
//   B1: per-bucket exclusive scan over chunks -> cursors[C][K], btot[K]
//   B2: exclusive scan of btot -> bstart[K+1]
//   C1: chunks scatter packed (dlocal<<18|src) into bucket regions (LDS cursors)
//   C2: per-bucket local node-hist + scan -> rowptr + node-sorted eidx
//       (each block writes only its own contiguous region -> ~1x write amp)
// Only LDS-scope atomics remain. Layers (pull-mode dwordx4 gather) unchanged.

typedef float f4 __attribute__((ext_vector_type(4)));

#define NCHUNK 512
#define MAXK 1024  // K = ceil(N/128); N=100000 -> 782

__device__ __forceinline__ float elu_f(float x) {
  return x > 0.0f ? x : expm1f(x);
}

__device__ __forceinline__ float rl(float v, int q) {
  return __int_as_float(__builtin_amdgcn_readlane(__float_as_int(v), q));
}

// ---------------- atomic-free CSR build ----------------

// A: per-chunk bucket histogram (bucket = node>>7)
__global__ __launch_bounds__(256) void bucket_hist_kernel(
    const int* __restrict__ dst, int* __restrict__ bhist, int E, int K, int chunk) {
  __shared__ int h[MAXK];
  for (int k = threadIdx.x; k < K; k += 256) h[k] = 0;
  __syncthreads();
  const int base = blockIdx.x * chunk;
  const int end = min(E, base + chunk);
  for (int e = base + threadIdx.x; e < end; e += 256)
    atomicAdd(&h[dst[e] >> 7], 1);
  __syncthreads();
  int* row = bhist + (long long)blockIdx.x * K;
  for (int k = threadIdx.x; k < K; k += 256) row[k] = h[k];
}

// B1: for bucket k, exclusive scan of bhist[c][k] over c -> cursors[c][k]; total -> btot[k]
__global__ __launch_bounds__(NCHUNK) void chunk_scan_kernel(
    const int* __restrict__ bhist, int* __restrict__ cursors,
    int* __restrict__ btot, int K) {
  __shared__ int s[NCHUNK];
  const int k = blockIdx.x;
  const int t = threadIdx.x;
  const int own = bhist[(long long)t * K + k];
  s[t] = own;
  __syncthreads();
#pragma unroll
  for (int off = 1; off < NCHUNK; off <<= 1) {
    int v = (t >= off) ? s[t - off] : 0;
    __syncthreads();
    s[t] += v;
    __syncthreads();
  }
  cursors[(long long)t * K + k] = s[t] - own;  // exclusive
  if (t == NCHUNK - 1) btot[k] = s[t];
}

// B2: exclusive scan of btot[0..K) -> bstart[0..K], bstart[K] = E
__global__ __launch_bounds__(1024) void bucket_scan_kernel(
    const int* __restrict__ btot, int* __restrict__ bstart, int K) {
  __shared__ int s[1024];
  const int t = threadIdx.x;
  const int own = (t < K) ? btot[t] : 0;
  s[t] = own;
  __syncthreads();
#pragma unroll
  for (int off = 1; off < 1024; off <<= 1) {
    int v = (t >= off) ? s[t - off] : 0;
    __syncthreads();
    s[t] += v;
    __syncthreads();
  }
  if (t < K) bstart[t] = s[t] - own;
  if (t == K - 1) bstart[K] = s[t];
}

// C1: scatter packed edges into bucket regions. packed = (dlocal<<18) | src.
__global__ __launch_bounds__(256) void bucket_scatter_kernel(
    const int* __restrict__ src, const int* __restrict__ dst,
    const int* __restrict__ cursors, const int* __restrict__ bstart,
    int* __restrict__ packed, int E, int K, int chunk) {
  __shared__ int cur[MAXK];
  const int c = blockIdx.x;
  for (int k = threadIdx.x; k < K; k += 256)
    cur[k] = cursors[(long long)c * K + k] + bstart[k];
  __syncthreads();
  const int base = c * chunk;
  const int end = min(E, base + chunk);
  for (int e = base + threadIdx.x; e < end; e += 256) {
    const int d = dst[e];
    const int k = d >> 7;
    const int p = atomicAdd(&cur[k], 1);
    packed[p] = ((d & 127) << 18) | src[e];
  }
}

// C2: per-bucket node hist + scan -> rowptr; reorder -> node-sorted eidx.
__global__ __launch_bounds__(256) void bucket_sort_kernel(
    const int* __restrict__ packed, const int* __restrict__ bstart,
    int* __restrict__ rowptr, int* __restrict__ eidx, int N, int E, int K) {
  __shared__ int hcnt[128];
  __shared__ int sc[128];
  __shared__ int ccur[128];
  const int k = blockIdx.x;
  const int t = threadIdx.x;
  const int n0 = k << 7;
  const int e0 = bstart[k];
  const int e1 = bstart[k + 1];
  if (t < 128) hcnt[t] = 0;
  __syncthreads();
  for (int e = e0 + t; e < e1; e += 256)
    atomicAdd(&hcnt[packed[e] >> 18], 1);
  __syncthreads();
  if (t < 128) sc[t] = hcnt[t];
  __syncthreads();
#pragma unroll
  for (int off = 1; off < 128; off <<= 1) {
    int v = 0;
    if (t < 128 && t >= off) v = sc[t - off];
    __syncthreads();
    if (t < 128) sc[t] += v;
    __syncthreads();
  }
  if (t < 128) {
    const int excl = sc[t] - hcnt[t];
    ccur[t] = excl;
    if (n0 + t < N) rowptr[n0 + t] = e0 + excl;
  }
  if (k == 0 && t == 0) rowptr[N] = E;
  __syncthreads();
  for (int e = e0 + t; e < e1; e += 256) {
    const int w = packed[e];
    const int dl = w >> 18;
    const int p = atomicAdd(&ccur[dl], 1);
    eidx[e0 + p] = w & 0x3FFFF;
  }
}

// ---------------- fused gather + MLP layers (round-4, unchanged) ----------------

template <int FO>
__global__ __launch_bounds__(256) void gin_layer64_kernel(
    const float* __restrict__ h, const int* __restrict__ rowptr,
    const int* __restrict__ eidx, const float* __restrict__ W,
    const float* __restrict__ b, float* __restrict__ out, int N) {
  const int lane = threadIdx.x & 63;
  const int grp = lane >> 4;
  const int li = lane & 15;
  const int wid = blockIdx.x * (blockDim.x >> 6) + (threadIdx.x >> 6);
  const int nw = gridDim.x * (blockDim.x >> 6);
  const int fo = lane & (FO - 1);
  float wcol[64];
#pragma unroll
  for (int k = 0; k < 64; ++k) wcol[k] = W[k * FO + fo];
  const float bias = b[fo];

  for (int n = wid; n < N; n += nw) {
    const int r0 = rowptr[n];
    const int cnt = rowptr[n + 1] - r0;
    const f4 self = *reinterpret_cast<const f4*>(h + (long long)n * 64 + li * 4);
    f4 a0 = {0.f, 0.f, 0.f, 0.f}, a1 = {0.f, 0.f, 0.f, 0.f};
    int i = grp;
    for (; i + 4 < cnt; i += 8) {
      const int s0 = eidx[r0 + i];
      const int s1 = eidx[r0 + i + 4];
      const f4 v0 = *reinterpret_cast<const f4*>(h + (long long)s0 * 64 + li * 4);
      const f4 v1 = *reinterpret_cast<const f4*>(h + (long long)s1 * 64 + li * 4);
      a0 += v0;
      a1 += v1;
    }
    if (i < cnt) {
      const int s = eidx[r0 + i];
      a0 += *reinterpret_cast<const f4*>(h + (long long)s * 64 + li * 4);
    }
    f4 a = a0 + a1;
    a.x += __shfl_xor(a.x, 16, 64); a.y += __shfl_xor(a.y, 16, 64);
    a.z += __shfl_xor(a.z, 16, 64); a.w += __shfl_xor(a.w, 16, 64);
    a.x += __shfl_xor(a.x, 32, 64); a.y += __shfl_xor(a.y, 32, 64);
    a.z += __shfl_xor(a.z, 32, 64); a.w += __shfl_xor(a.w, 32, 64);
    a += self;
    float o0 = bias, o1 = 0.0f;
#pragma unroll
    for (int q = 0; q < 16; ++q) {
      o0 = fmaf(rl(a.x, q), wcol[4 * q + 0], o0);
      o1 = fmaf(rl(a.y, q), wcol[4 * q + 1], o1);
      o0 = fmaf(rl(a.z, q), wcol[4 * q + 2], o0);
      o1 = fmaf(rl(a.w, q), wcol[4 * q + 3], o1);
    }
    if (lane < FO) out[(long long)n * FO + lane] = elu_f(o0 + o1);
  }
}

__global__ __launch_bounds__(256) void gin_layer32_kernel(
    const float* __restrict__ h, const int* __restrict__ rowptr,
    const int* __restrict__ eidx, const float* __restrict__ W,
    const float* __restrict__ b, float* __restrict__ out, int N) {
  const int lane = threadIdx.x & 63;
  const int grp = lane >> 3;
  const int li = lane & 7;
  const int wid = blockIdx.x * (blockDim.x >> 6) + (threadIdx.x >> 6);
  const int nw = gridDim.x * (blockDim.x >> 6);
  float wcol[32];
#pragma unroll
  for (int k = 0; k < 32; ++k) wcol[k] = W[k * 64 + lane];
  const float bias = b[lane];

  for (int n = wid; n < N; n += nw) {
    const int r0 = rowptr[n];
    const int cnt = rowptr[n + 1] - r0;
    const f4 self = *reinterpret_cast<const f4*>(h + (long long)n * 32 + li * 4);
    f4 a0 = {0.f, 0.f, 0.f, 0.f}, a1 = {0.f, 0.f, 0.f, 0.f};
    int i = grp;
    for (; i + 8 < cnt; i += 16) {
      const int s0 = eidx[r0 + i];
      const int s1 = eidx[r0 + i + 8];
      const f4 v0 = *reinterpret_cast<const f4*>(h + (long long)s0 * 32 + li * 4);
      const f4 v1 = *reinterpret_cast<const f4*>(h + (long long)s1 * 32 + li * 4);
      a0 += v0;
      a1 += v1;
    }
    if (i < cnt) {
      const int s = eidx[r0 + i];
      a0 += *reinterpret_cast<const f4*>(h + (long long)s * 32 + li * 4);
    }
    f4 a = a0 + a1;
    a.x += __shfl_xor(a.x, 8, 64);  a.y += __shfl_xor(a.y, 8, 64);
    a.z += __shfl_xor(a.z, 8, 64);  a.w += __shfl_xor(a.w, 8, 64);
    a.x += __shfl_xor(a.x, 16, 64); a.y += __shfl_xor(a.y, 16, 64);
    a.z += __shfl_xor(a.z, 16, 64); a.w += __shfl_xor(a.w, 16, 64);
    a.x += __shfl_xor(a.x, 32, 64); a.y += __shfl_xor(a.y, 32, 64);
    a.z += __shfl_xor(a.z, 32, 64); a.w += __shfl_xor(a.w, 32, 64);
    a += self;
    float o0 = bias, o1 = 0.0f;
#pragma unroll
    for (int q = 0; q < 8; ++q) {
      o0 = fmaf(rl(a.x, q), wcol[4 * q + 0], o0);
      o1 = fmaf(rl(a.y, q), wcol[4 * q + 1], o1);
      o0 = fmaf(rl(a.z, q), wcol[4 * q + 2], o0);
      o1 = fmaf(rl(a.w, q), wcol[4 * q + 3], o1);
    }
    out[(long long)n * 64 + lane] = elu_f(o0 + o1);
  }
}

// ---------------- pooling + head ----------------

__global__ void pool_kernel(const float* __restrict__ h,
                            const int* __restrict__ batch,
                            float* __restrict__ sums,
                            float* __restrict__ cnts,
                            int N) {
  const int groupsPerBlock = blockDim.x >> 6;
  const int grp = blockIdx.x * groupsPerBlock + (threadIdx.x >> 6);
  const int ngrp = gridDim.x * groupsPerBlock;
  const int f = threadIdx.x & 63;
  const int chunk = (N + ngrp - 1) / ngrp;
  const int n0 = grp * chunk;
  const int n1 = min(N, n0 + chunk);
  if (n0 >= n1) return;
  int g = batch[n0];
  float acc = 0.0f;
  float cnt = 0.0f;
  for (int n = n0; n < n1; ++n) {
    const int bg = batch[n];
    if (bg != g) {
      atomicAdd(&sums[(long long)g * 64 + f], acc);
      if (f == 0) atomicAdd(&cnts[g], cnt);
      acc = 0.0f;
      cnt = 0.0f;
      g = bg;
    }
    acc += h[(long long)n * 64 + f];
    cnt += 1.0f;
  }
  atomicAdd(&sums[(long long)g * 64 + f], acc);
  if (f == 0) atomicAdd(&cnts[g], cnt);
}

__global__ void head_kernel(const float* __restrict__ sums,
                            const float* __restrict__ cnts,
                            const float* __restrict__ Wf1, const float* __restrict__ bf1,
                            const float* __restrict__ Wf2, const float* __restrict__ bf2,
                            const float* __restrict__ Wf3, const float* __restrict__ bf3,
                            float* __restrict__ out, int G) {
  __shared__ float s0[64];
  __shared__ float s1[64];
  __shared__ float s2[32];
  const int g = blockIdx.x;
  const int t = threadIdx.x;
  const float c = fmaxf(cnts[g], 1.0f);
  s0[t] = sums[(long long)g * 64 + t] / c;
  __syncthreads();
  float acc = bf1[t];
#pragma unroll
  for (int k = 0; k < 64; ++k) acc += s0[k] * Wf1[k * 64 + t];
  s1[t] = elu_f(acc);
  __syncthreads();
  if (t < 32) {
    float a2 = bf2[t];
#pragma unroll
    for (int k = 0; k < 64; ++k) a2 += s1[k] * Wf2[k * 32 + t];
    s2[t] = elu_f(a2) * Wf3[t];
  }
  __syncthreads();
  if (t == 0) {
    float r = bf3[0];
#pragma unroll
    for (int k = 0; k < 32; ++k) r += s2[k];
    out[g] = r;
  }
}

extern "C" void kernel_launch(void* const* d_in, const int* in_sizes, int n_in,
                              void* d_out, int out_size, void* d_ws, size_t ws_size,
                              hipStream_t stream) {
  const float* x   = (const float*)d_in[0];
  const int* ei    = (const int*)d_in[1];
  const int* batch = (const int*)d_in[2];
  const float* W1  = (const float*)d_in[4];
  const float* b1  = (const float*)d_in[5];
  const float* W2  = (const float*)d_in[6];
  const float* b2  = (const float*)d_in[7];
  const float* W3  = (const float*)d_in[8];
  const float* b3  = (const float*)d_in[9];
  const float* Wf1 = (const float*)d_in[10];
  const float* bf1 = (const float*)d_in[11];
  const float* Wf2 = (const float*)d_in[12];
  const float* bf2 = (const float*)d_in[13];
  const float* Wf3 = (const float*)d_in[14];
  const float* bf3 = (const float*)d_in[15];

  const int N = in_sizes[0] / 64;
  const int E = in_sizes[1] / 2;
  const int G = out_size;
  const int* src = ei;
  const int* dst = ei + E;
  const int K = (N + 127) >> 7;                 // buckets of 128 nodes (<= MAXK)
  const int chunk = (E + NCHUNK - 1) / NCHUNK;

  char* ws = (char*)d_ws;
  size_t off = 0;
  auto alloc = [&](size_t bytes) -> void* {
    void* p = ws + off;
    off = (off + bytes + 255) & ~(size_t)255;
    return p;
  };
  int* bhist   = (int*)alloc((size_t)NCHUNK * K * 4);
  int* cursors = (int*)alloc((size_t)NCHUNK * K * 4);
  int* btot    = (int*)alloc((size_t)K * 4);
  int* bstart  = (int*)alloc((size_t)(K + 1) * 4);
  int* rowptr  = (int*)alloc((size_t)(N + 1) * 4);
  int* eidx    = (int*)alloc((size_t)E * 4);
  float* hA    = (float*)alloc((size_t)N * 64 * 4);
  float* hB    = (float*)alloc((size_t)N * 64 * 4);
  float* sums  = (float*)alloc((size_t)G * 64 * 4);
  float* cnts  = (float*)alloc((size_t)G * 4);
  int* packed  = (int*)hB;  // alias: packed consumed before hB first written
  float* out   = (float*)d_out;

  // ---- atomic-free CSR build ----
  bucket_hist_kernel<<<NCHUNK, 256, 0, stream>>>(dst, bhist, E, K, chunk);
  chunk_scan_kernel<<<K, NCHUNK, 0, stream>>>(bhist, cursors, btot, K);
  bucket_scan_kernel<<<1, 1024, 0, stream>>>(btot, bstart, K);
  bucket_scatter_kernel<<<NCHUNK, 256, 0, stream>>>(src, dst, cursors, bstart,
                                                    packed, E, K, chunk);
  bucket_sort_kernel<<<K, 256, 0, stream>>>(packed, bstart, rowptr, eidx, N, E, K);

  // ---- layers ----
  gin_layer64_kernel<32><<<2048, 256, 0, stream>>>(x,  rowptr, eidx, W1, b1, hA, N);
  gin_layer32_kernel<<<2048, 256, 0, stream>>>(hA, rowptr, eidx, W2, b2, hB, N);
  gin_layer64_kernel<64><<<2048, 256, 0, stream>>>(hB, rowptr, eidx, W3, b3, hA, N);

  // ---- mean pool + head ----
  hipMemsetAsync(sums, 0, (size_t)G * 64 * 4, stream);
  hipMemsetAsync(cnts, 0, (size_t)G * 4, stream);
  pool_kernel<<<512, 256, 0, stream>>>(hA, batch, sums, cnts, N);
  head_kernel<<<G, 64, 0, stream>>>(sums, cnts, Wf1, bf1, Wf2, bf2, Wf3, bf3, out, G);
}

// Round 7
// 473.710 us; speedup vs baseline: 4.3446x; 1.0968x over previous
//
#include <hip/hip_runtime.h>
#include <hip/hip_bf16.h>

// GIN 3-layer + mean-pool + MLP head for MI355X (gfx950).
//
// Round-7: layers are fabric/L3-fetch bound (FETCH 368MB @ ~3TB/s = dur).
// Store features as bf16 -> halves gather bytes. f32 x converted once; all
// accumulation/MLP in f32 (exact bf16->f32 unpack; RNE f32->bf16 store).
// FI=64: 8 lanes x 16B per row, 8 edges/instr. FI=32: 4 lanes/row, 16/instr.
// CSR build = round-5 atomic-free two-level counting sort (unchanged).

typedef float f4 __attribute__((ext_vector_type(4)));

#define NCHUNK 512
#define MAXK 1024  // K = ceil(N/128); N=100000 -> 782

__device__ __forceinline__ float elu_f(float x) {
  return x > 0.0f ? x : expm1f(x);
}

__device__ __forceinline__ float rl(float v, int q) {
  return __int_as_float(__builtin_amdgcn_readlane(__float_as_int(v), q));
}

__device__ __forceinline__ unsigned short f2bf(float f) {
  unsigned int u = __float_as_uint(f);
  u = (u + 0x7FFFu + ((u >> 16) & 1u)) >> 16;  // RNE
  return (unsigned short)u;
}

// unpack uint4 = 8 bf16 and accumulate into a[0..7]
__device__ __forceinline__ void acc_add8(float* a, const uint4 w) {
  a[0] += __uint_as_float(w.x << 16);
  a[1] += __uint_as_float(w.x & 0xffff0000u);
  a[2] += __uint_as_float(w.y << 16);
  a[3] += __uint_as_float(w.y & 0xffff0000u);
  a[4] += __uint_as_float(w.z << 16);
  a[5] += __uint_as_float(w.z & 0xffff0000u);
  a[6] += __uint_as_float(w.w << 16);
  a[7] += __uint_as_float(w.w & 0xffff0000u);
}

// ---------------- f32 -> bf16 conversion ----------------

__global__ __launch_bounds__(256) void cvt_bf16_kernel(
    const float* __restrict__ in, unsigned short* __restrict__ out, int n4) {
  typedef unsigned short us4 __attribute__((ext_vector_type(4)));
  const int stride = gridDim.x * blockDim.x;
  for (int i = blockIdx.x * blockDim.x + threadIdx.x; i < n4; i += stride) {
    const f4 v = *reinterpret_cast<const f4*>(in + (long long)i * 4);
    us4 o;
    o.x = f2bf(v.x); o.y = f2bf(v.y); o.z = f2bf(v.z); o.w = f2bf(v.w);
    *reinterpret_cast<us4*>(out + (long long)i * 4) = o;
  }
}

// ---------------- atomic-free CSR build (round-5, unchanged) ----------------

__global__ __launch_bounds__(256) void bucket_hist_kernel(
    const int* __restrict__ dst, int* __restrict__ bhist, int E, int K, int chunk) {
  __shared__ int h[MAXK];
  for (int k = threadIdx.x; k < K; k += 256) h[k] = 0;
  __syncthreads();
  const int base = blockIdx.x * chunk;
  const int end = min(E, base + chunk);
  for (int e = base + threadIdx.x; e < end; e += 256)
    atomicAdd(&h[dst[e] >> 7], 1);
  __syncthreads();
  int* row = bhist + (long long)blockIdx.x * K;
  for (int k = threadIdx.x; k < K; k += 256) row[k] = h[k];
}

__global__ __launch_bounds__(NCHUNK) void chunk_scan_kernel(
    const int* __restrict__ bhist, int* __restrict__ cursors,
    int* __restrict__ btot, int K) {
  __shared__ int s[NCHUNK];
  const int k = blockIdx.x;
  const int t = threadIdx.x;
  const int own = bhist[(long long)t * K + k];
  s[t] = own;
  __syncthreads();
#pragma unroll
  for (int off = 1; off < NCHUNK; off <<= 1) {
    int v = (t >= off) ? s[t - off] : 0;
    __syncthreads();
    s[t] += v;
    __syncthreads();
  }
  cursors[(long long)t * K + k] = s[t] - own;
  if (t == NCHUNK - 1) btot[k] = s[t];
}

__global__ __launch_bounds__(1024) void bucket_scan_kernel(
    const int* __restrict__ btot, int* __restrict__ bstart, int K) {
  __shared__ int s[1024];
  const int t = threadIdx.x;
  const int own = (t < K) ? btot[t] : 0;
  s[t] = own;
  __syncthreads();
#pragma unroll
  for (int off = 1; off < 1024; off <<= 1) {
    int v = (t >= off) ? s[t - off] : 0;
    __syncthreads();
    s[t] += v;
    __syncthreads();
  }
  if (t < K) bstart[t] = s[t] - own;
  if (t == K - 1) bstart[K] = s[t];
}

__global__ __launch_bounds__(256) void bucket_scatter_kernel(
    const int* __restrict__ src, const int* __restrict__ dst,
    const int* __restrict__ cursors, const int* __restrict__ bstart,
    int* __restrict__ packed, int E, int K, int chunk) {
  __shared__ int cur[MAXK];
  const int c = blockIdx.x;
  for (int k = threadIdx.x; k < K; k += 256)
    cur[k] = cursors[(long long)c * K + k] + bstart[k];
  __syncthreads();
  const int base = c * chunk;
  const int end = min(E, base + chunk);
  for (int e = base + threadIdx.x; e < end; e += 256) {
    const int d = dst[e];
    const int k = d >> 7;
    const int p = atomicAdd(&cur[k], 1);
    packed[p] = ((d & 127) << 18) | src[e];
  }
}

__global__ __launch_bounds__(256) void bucket_sort_kernel(
    const int* __restrict__ packed, const int* __restrict__ bstart,
    int* __restrict__ rowptr, int* __restrict__ eidx, int N, int E, int K) {
  __shared__ int hcnt[128];
  __shared__ int sc[128];
  __shared__ int ccur[128];
  const int k = blockIdx.x;
  const int t = threadIdx.x;
  const int n0 = k << 7;
  const int e0 = bstart[k];
  const int e1 = bstart[k + 1];
  if (t < 128) hcnt[t] = 0;
  __syncthreads();
  for (int e = e0 + t; e < e1; e += 256)
    atomicAdd(&hcnt[packed[e] >> 18], 1);
  __syncthreads();
  if (t < 128) sc[t] = hcnt[t];
  __syncthreads();
#pragma unroll
  for (int off = 1; off < 128; off <<= 1) {
    int v = 0;
    if (t < 128 && t >= off) v = sc[t - off];
    __syncthreads();
    if (t < 128) sc[t] += v;
    __syncthreads();
  }
  if (t < 128) {
    const int excl = sc[t] - hcnt[t];
    ccur[t] = excl;
    if (n0 + t < N) rowptr[n0 + t] = e0 + excl;
  }
  if (k == 0 && t == 0) rowptr[N] = E;
  __syncthreads();
  for (int e = e0 + t; e < e1; e += 256) {
    const int w = packed[e];
    const int dl = w >> 18;
    const int p = atomicAdd(&ccur[dl], 1);
    eidx[e0 + p] = w & 0x3FFFF;
  }
}

// ---------------- fused bf16 gather + MLP layers ----------------

// FI=64 bf16: 8 groups of 8 lanes; row = 128B; 8 edges/instr, unroll 2.
template <int FO>
__global__ __launch_bounds__(256) void gin_layer64_kernel(
    const unsigned short* __restrict__ h, const int* __restrict__ rowptr,
    const int* __restrict__ eidx, const float* __restrict__ W,
    const float* __restrict__ b, unsigned short* __restrict__ out, int N) {
  const int lane = threadIdx.x & 63;
  const int grp = lane >> 3;       // edge slot 0..7
  const int li = lane & 7;         // features li*8 .. li*8+7
  const int wid = blockIdx.x * (blockDim.x >> 6) + (threadIdx.x >> 6);
  const int nw = gridDim.x * (blockDim.x >> 6);
  const int fo = lane & (FO - 1);
  float wcol[64];
#pragma unroll
  for (int k = 0; k < 64; ++k) wcol[k] = W[k * FO + fo];
  const float bias = b[fo];

  for (int n = wid; n < N; n += nw) {
    const int r0 = rowptr[n];
    const int cnt = rowptr[n + 1] - r0;
    float a[8] = {0.f, 0.f, 0.f, 0.f, 0.f, 0.f, 0.f, 0.f};
    int i = grp;
    for (; i + 8 < cnt; i += 16) {
      const int s0 = eidx[r0 + i];
      const int s1 = eidx[r0 + i + 8];
      const uint4 w0 = *reinterpret_cast<const uint4*>(h + (long long)s0 * 64 + li * 8);
      const uint4 w1 = *reinterpret_cast<const uint4*>(h + (long long)s1 * 64 + li * 8);
      acc_add8(a, w0);
      acc_add8(a, w1);
    }
    if (i < cnt) {
      const int s = eidx[r0 + i];
      acc_add8(a, *reinterpret_cast<const uint4*>(h + (long long)s * 64 + li * 8));
    }
#pragma unroll
    for (int j = 0; j < 8; ++j) {
      a[j] += __shfl_xor(a[j], 8, 64);
      a[j] += __shfl_xor(a[j], 16, 64);
      a[j] += __shfl_xor(a[j], 32, 64);
    }
    // self term (each lane adds its own li-chunk once, post-combine)
    acc_add8(a, *reinterpret_cast<const uint4*>(h + (long long)n * 64 + li * 8));
    float o0 = bias, o1 = 0.0f;
#pragma unroll
    for (int k = 0; k < 64; k += 2) {
      o0 = fmaf(rl(a[k & 7], k >> 3), wcol[k], o0);
      o1 = fmaf(rl(a[(k + 1) & 7], (k + 1) >> 3), wcol[k + 1], o1);
    }
    if (lane < FO) out[(long long)n * FO + lane] = f2bf(elu_f(o0 + o1));
  }
}

// FI=32 bf16, FO=64: 16 groups of 4 lanes; row = 64B; 16 edges/instr, unroll 2.
__global__ __launch_bounds__(256) void gin_layer32_kernel(
    const unsigned short* __restrict__ h, const int* __restrict__ rowptr,
    const int* __restrict__ eidx, const float* __restrict__ W,
    const float* __restrict__ b, unsigned short* __restrict__ out, int N) {
  const int lane = threadIdx.x & 63;
  const int grp = lane >> 2;       // edge slot 0..15
  const int li = lane & 3;         // features li*8 .. li*8+7
  const int wid = blockIdx.x * (blockDim.x >> 6) + (threadIdx.x >> 6);
  const int nw = gridDim.x * (blockDim.x >> 6);
  float wcol[32];
#pragma unroll
  for (int k = 0; k < 32; ++k) wcol[k] = W[k * 64 + lane];
  const float bias = b[lane];

  for (int n = wid; n < N; n += nw) {
    const int r0 = rowptr[n];
    const int cnt = rowptr[n + 1] - r0;
    float a[8] = {0.f, 0.f, 0.f, 0.f, 0.f, 0.f, 0.f, 0.f};
    int i = grp;
    for (; i + 16 < cnt; i += 32) {
      const int s0 = eidx[r0 + i];
      const int s1 = eidx[r0 + i + 16];
      const uint4 w0 = *reinterpret_cast<const uint4*>(h + (long long)s0 * 32 + li * 8);
      const uint4 w1 = *reinterpret_cast<const uint4*>(h + (long long)s1 * 32 + li * 8);
      acc_add8(a, w0);
      acc_add8(a, w1);
    }
    if (i < cnt) {
      const int s = eidx[r0 + i];
      acc_add8(a, *reinterpret_cast<const uint4*>(h + (long long)s * 32 + li * 8));
    }
#pragma unroll
    for (int j = 0; j < 8; ++j) {
      a[j] += __shfl_xor(a[j], 4, 64);
      a[j] += __shfl_xor(a[j], 8, 64);
      a[j] += __shfl_xor(a[j], 16, 64);
      a[j] += __shfl_xor(a[j], 32, 64);
    }
    acc_add8(a, *reinterpret_cast<const uint4*>(h + (long long)n * 32 + li * 8));
    float o0 = bias, o1 = 0.0f;
#pragma unroll
    for (int k = 0; k < 32; k += 2) {
      o0 = fmaf(rl(a[k & 7], k >> 3), wcol[k], o0);
      o1 = fmaf(rl(a[(k + 1) & 7], (k + 1) >> 3), wcol[k + 1], o1);
    }
    out[(long long)n * 64 + lane] = f2bf(elu_f(o0 + o1));
  }
}

// ---------------- pooling + head ----------------

__global__ void pool_kernel(const unsigned short* __restrict__ h,
                            const int* __restrict__ batch,
                            float* __restrict__ sums,
                            float* __restrict__ cnts,
                            int N) {
  const int groupsPerBlock = blockDim.x >> 6;
  const int grp = blockIdx.x * groupsPerBlock + (threadIdx.x >> 6);
  const int ngrp = gridDim.x * groupsPerBlock;
  const int f = threadIdx.x & 63;
  const int chunk = (N + ngrp - 1) / ngrp;
  const int n0 = grp * chunk;
  const int n1 = min(N, n0 + chunk);
  if (n0 >= n1) return;
  int g = batch[n0];
  float acc = 0.0f;
  float cnt = 0.0f;
  for (int n = n0; n < n1; ++n) {
    const int bg = batch[n];
    if (bg != g) {
      atomicAdd(&sums[(long long)g * 64 + f], acc);
      if (f == 0) atomicAdd(&cnts[g], cnt);
      acc = 0.0f;
      cnt = 0.0f;
      g = bg;
    }
    acc += __uint_as_float((unsigned int)h[(long long)n * 64 + f] << 16);
    cnt += 1.0f;
  }
  atomicAdd(&sums[(long long)g * 64 + f], acc);
  if (f == 0) atomicAdd(&cnts[g], cnt);
}

__global__ void head_kernel(const float* __restrict__ sums,
                            const float* __restrict__ cnts,
                            const float* __restrict__ Wf1, const float* __restrict__ bf1,
                            const float* __restrict__ Wf2, const float* __restrict__ bf2,
                            const float* __restrict__ Wf3, const float* __restrict__ bf3,
                            float* __restrict__ out, int G) {
  __shared__ float s0[64];
  __shared__ float s1[64];
  __shared__ float s2[32];
  const int g = blockIdx.x;
  const int t = threadIdx.x;
  const float c = fmaxf(cnts[g], 1.0f);
  s0[t] = sums[(long long)g * 64 + t] / c;
  __syncthreads();
  float acc = bf1[t];
#pragma unroll
  for (int k = 0; k < 64; ++k) acc += s0[k] * Wf1[k * 64 + t];
  s1[t] = elu_f(acc);
  __syncthreads();
  if (t < 32) {
    float a2 = bf2[t];
#pragma unroll
    for (int k = 0; k < 64; ++k) a2 += s1[k] * Wf2[k * 32 + t];
    s2[t] = elu_f(a2) * Wf3[t];
  }
  __syncthreads();
  if (t == 0) {
    float r = bf3[0];
#pragma unroll
    for (int k = 0; k < 32; ++k) r += s2[k];
    out[g] = r;
  }
}

extern "C" void kernel_launch(void* const* d_in, const int* in_sizes, int n_in,
                              void* d_out, int out_size, void* d_ws, size_t ws_size,
                              hipStream_t stream) {
  const float* x   = (const float*)d_in[0];
  const int* ei    = (const int*)d_in[1];
  const int* batch = (const int*)d_in[2];
  const float* W1  = (const float*)d_in[4];
  const float* b1  = (const float*)d_in[5];
  const float* W2  = (const float*)d_in[6];
  const float* b2  = (const float*)d_in[7];
  const float* W3  = (const float*)d_in[8];
  const float* b3  = (const float*)d_in[9];
  const float* Wf1 = (const float*)d_in[10];
  const float* bf1 = (const float*)d_in[11];
  const float* Wf2 = (const float*)d_in[12];
  const float* bf2 = (const float*)d_in[13];
  const float* Wf3 = (const float*)d_in[14];
  const float* bf3 = (const float*)d_in[15];

  const int N = in_sizes[0] / 64;
  const int E = in_sizes[1] / 2;
  const int G = out_size;
  const int* src = ei;
  const int* dst = ei + E;
  const int K = (N + 127) >> 7;
  const int chunk = (E + NCHUNK - 1) / NCHUNK;

  char* ws = (char*)d_ws;
  size_t off = 0;
  auto alloc = [&](size_t bytes) -> void* {
    void* p = ws + off;
    off = (off + bytes + 255) & ~(size_t)255;
    return p;
  };
  int* bhist   = (int*)alloc((size_t)NCHUNK * K * 4);
  int* cursors = (int*)alloc((size_t)NCHUNK * K * 4);
  int* btot    = (int*)alloc((size_t)K * 4);
  int* bstart  = (int*)alloc((size_t)(K + 1) * 4);
  int* rowptr  = (int*)alloc((size_t)(N + 1) * 4);
  int* eidx    = (int*)alloc((size_t)E * 4);
  int* packed  = (int*)alloc((size_t)E * 4);
  unsigned short* xb = (unsigned short*)alloc((size_t)N * 64 * 2);
  unsigned short* hA = (unsigned short*)alloc((size_t)N * 64 * 2);
  unsigned short* hB = (unsigned short*)alloc((size_t)N * 64 * 2);
  float* sums  = (float*)alloc((size_t)G * 64 * 4);
  float* cnts  = (float*)alloc((size_t)G * 4);
  float* out   = (float*)d_out;

  // ---- x -> bf16 (overlaps nothing, cheap) ----
  cvt_bf16_kernel<<<1024, 256, 0, stream>>>(x, xb, N * 16);

  // ---- atomic-free CSR build ----
  bucket_hist_kernel<<<NCHUNK, 256, 0, stream>>>(dst, bhist, E, K, chunk);
  chunk_scan_kernel<<<K, NCHUNK, 0, stream>>>(bhist, cursors, btot, K);
  bucket_scan_kernel<<<1, 1024, 0, stream>>>(btot, bstart, K);
  bucket_scatter_kernel<<<NCHUNK, 256, 0, stream>>>(src, dst, cursors, bstart,
                                                    packed, E, K, chunk);
  bucket_sort_kernel<<<K, 256, 0, stream>>>(packed, bstart, rowptr, eidx, N, E, K);

  // ---- layers (bf16 features) ----
  gin_layer64_kernel<32><<<2048, 256, 0, stream>>>(xb, rowptr, eidx, W1, b1, hA, N);
  gin_layer32_kernel<<<2048, 256, 0, stream>>>(hA, rowptr, eidx, W2, b2, hB, N);
  gin_layer64_kernel<64><<<2048, 256, 0, stream>>>(hB, rowptr, eidx, W3, b3, hA, N);

  // ---- mean pool + head ----
  hipMemsetAsync(sums, 0, (size_t)G * 64 * 4, stream);
  hipMemsetAsync(cnts, 0, (size_t)G * 4, stream);
  pool_kernel<<<512, 256, 0, stream>>>(hA, batch, sums, cnts, N);
  head_kernel<<<G, 64, 0, stream>>>(sums, cnts, Wf1, bf1, Wf2, bf2, Wf3, bf3, out, G);
}